// Round 11
// baseline (622.031 us; speedup 1.0000x reference)
//
#include <hip/hip_runtime.h>

// Row-wise top-K(32) of relu(A), zero elsewhere. N=8192 fp32 per row.
// WAVE-AUTONOMOUS: one 64-lane wave per row, 4 waves/block, ZERO barriers.
// (R3/R7/R8: three block-level structures all pinned at ~92 us with ideal
//  traffic -> the block-wide load->sync->select->sync->emit fences are the
//  limiter. Removing them lets 20-32 independent per-CU streams overlap
//  every phase.)
//  - A read from global EXACTLY ONCE per row (R4)
//  - zero burst issued BEFORE selection; vmcnt(0) only right before the
//    <=32 scattered patch stores (lands in L2 lines just written)
//  - per-wave LDS slice ~4.8 KB: hist[512] + cand[256] + binB[96]
// Exact per-wave fallback: 32 masked argmax full-row rescans (any input,
// exact ties; L2-hot; ~never taken for N(0,1) rows).

constexpr int N     = 8192;
constexpr int K     = 32;
constexpr int HB    = 512;      // values > 2.0: (bits>>21)-512 in [0, 512)
constexpr int CAP   = 256;      // candidates > 2.0 (mean ~186, sd ~13.5)
constexpr int BB    = 96;       // cutoff-bin members (mean ~52, +6 sigma)
constexpr int BLOCK = 256;
constexpr int WPB   = 4;        // waves (rows) per block
constexpr float TSPEC = 2.0f;

typedef float f4 __attribute__((ext_vector_type(4)));

__global__ __launch_bounds__(BLOCK)
void topk_wave_kernel(const float* __restrict__ A, float* __restrict__ Out) {
    const int tid  = threadIdx.x;
    const int lane = tid & 63;
    const int w    = tid >> 6;
    const int row  = blockIdx.x * WPB + w;

    __shared__ unsigned hist_s[WPB][HB];
    __shared__ float    cv_s[WPB][CAP];
    __shared__ int      cc_s[WPB][CAP];
    __shared__ float    bbv_s[WPB][BB];
    __shared__ int      bbc_s[WPB][BB];

    unsigned* hist = hist_s[w];
    float*    cv   = cv_s[w];
    int*      cc   = cc_s[w];
    float*    bbv  = bbv_s[w];
    int*      bbc  = bbc_s[w];

    // zero own hist (wave-private; same-wave LDS ordering, no barrier)
    #pragma unroll
    for (int i = 0; i < HB / 64; ++i) hist[i * 64 + lane] = 0u;

    const f4* __restrict__ Arow  = reinterpret_cast<const f4*>(A + (size_t)row * N);
    f4*       __restrict__ Orow4 = reinterpret_cast<f4*>(Out + (size_t)row * N);
    float*    __restrict__ Orow  = Out + (size_t)row * N;

    // ---- load row once: histogram + ballot-compacted candidate list ----
    int Cb = 0;                                  // wave-uniform running count
    #pragma unroll 4
    for (int it = 0; it < 32; ++it) {
        f4 v = Arow[it * 64 + lane];
        #pragma unroll
        for (int c = 0; c < 4; ++c) {
            float f = v[c];
            bool flag = f > TSPEC;
            unsigned long long m = __ballot(flag);
            if (flag) {
                atomicAdd(&hist[(__float_as_uint(f) >> 21) - 512], 1u);
                int pos = Cb + (int)__popcll(m & ((1ull << lane) - 1ull));
                if (pos < CAP) { cv[pos] = f; cc[pos] = (it * 64 + lane) * 4 + c; }
            }
            Cb += (int)__popcll(m);
        }
    }

    // ---- zero burst: no dependencies; drains under the selection math ----
    const f4 z = {0.0f, 0.0f, 0.0f, 0.0f};
    #pragma unroll 8
    for (int it = 0; it < 32; ++it) Orow4[it * 64 + lane] = z;

    // ---- selection (wave-private, registers + shuffles + LDS broadcast) ----
    bool fb = (Cb < K) || (Cb > CAP);
    float vR = __int_as_float(0x7f800000);
    int   cR = -1, B = -1;
    if (!fb) {
        // cutoff bin over 512 bins, 8 bins/lane
        unsigned s = 0;
        #pragma unroll
        for (int i = 0; i < 8; ++i) s += hist[lane * 8 + i];
        unsigned acc = s;                        // inclusive suffix over lanes
        #pragma unroll
        for (int off = 1; off < 64; off <<= 1) {
            unsigned t = __shfl_down(acc, off, 64);
            if (lane + off < 64) acc += t;
        }
        unsigned long long m = __ballot(acc >= (unsigned)K);   // != 0 (Cb>=K)
        int g = 63 - __clzll((long long)m);
        unsigned above = (g < 63) ? (unsigned)__shfl((int)acc, g + 1, 64) : 0u;
        unsigned h  = (lane < 8) ? hist[g * 8 + lane] : 0u;
        unsigned a2 = h;
        #pragma unroll
        for (int off = 1; off < 64; off <<= 1) {
            unsigned t = __shfl_down(a2, off, 64);
            if (lane + off < 64) a2 += t;
        }
        unsigned long long m2 = __ballot(above + a2 >= (unsigned)K);
        int bl = 63 - __clzll((long long)m2);
        B = g * 8 + bl;
        const int G = (int)(above + (unsigned)__shfl((int)a2, bl, 64)
                                  - (unsigned)__shfl((int)h,  bl, 64));
        const int R = K - G;                     // 1 <= R <= T

        // compact bin-B members into bb (wave-private LDS)
        int T = 0;
        #pragma unroll
        for (int s2 = 0; s2 < CAP / 64; ++s2) {
            int j = s2 * 64 + lane;
            bool flag = false; float fv = 0.0f; int fc = 0;
            if (j < Cb) {
                fv = cv[j];
                if ((int)((__float_as_uint(fv) >> 21) - 512) == B) { flag = true; fc = cc[j]; }
            }
            unsigned long long mm = __ballot(flag);
            if (flag) {
                int pos = T + (int)__popcll(mm & ((1ull << lane) - 1ull));
                if (pos < BB) { bbv[pos] = fv; bbc[pos] = fc; }
            }
            T += (int)__popcll(mm);
        }
        if (T > BB) {
            fb = true;
        } else {
            // exact (val desc, col asc) rank of each bb member; boundary = rank R-1
            float mv0 = -1.0f, mv1 = -1.0f; int mc0 = 0x7fffffff, mc1 = 0x7fffffff;
            if (lane      < T) { mv0 = bbv[lane];      mc0 = bbc[lane]; }
            if (lane + 64 < T) { mv1 = bbv[lane + 64]; mc1 = bbc[lane + 64]; }
            int r0 = 0, r1 = 0;
            for (int j = 0; j < T; ++j) {        // LDS broadcast reads
                float vj = bbv[j]; int cj = bbc[j];
                if (vj > mv0 || (vj == mv0 && cj < mc0)) r0++;
                if (vj > mv1 || (vj == mv1 && cj < mc1)) r1++;
            }
            bool found = false; float bv = 0.0f; int bc = -1;
            if (lane      < T && r0 == R - 1) { bv = mv0; bc = mc0; found = true; }
            if (lane + 64 < T && r1 == R - 1) { bv = mv1; bc = mc1; found = true; }
            unsigned long long bm = __ballot(found);   // exactly one lane
            int src = (int)__ffsll((long long)bm) - 1;
            vR = __shfl(bv, src, 64);
            cR = __shfl(bc, src, 64);
        }
    }

    if (!fb) {
        // ---- patch: zeros landed -> scatter the K kept pairs (L2 merge) ----
        asm volatile("s_waitcnt vmcnt(0)" ::: "memory");
        #pragma unroll
        for (int s2 = 0; s2 < CAP / 64; ++s2) {
            int j = s2 * 64 + lane;
            if (j < Cb) {
                float f = cv[j]; int c = cc[j];
                int b = (int)((__float_as_uint(f) >> 21) - 512);
                if (b > B || (b == B && (f > vR || (f == vR && c <= cR))))
                    Orow[c] = f;
            }
        }
        return;
    }

    // ---- exact per-wave fallback: 32 masked argmax rescans (L2-hot) ----
    asm volatile("s_waitcnt vmcnt(0)" ::: "memory");   // row fully zeroed
    float pv = __int_as_float(0x7f800000); int pc = -1;   // prev selected
    float selv = 0.0f; int selc = -1;                     // lane k holds k-th
    for (int k = 0; k < K; ++k) {
        float bmv = 0.0f; int bmc = 0x7fffffff;
        for (int it = 0; it < 32; ++it) {
            f4 v = Arow[it * 64 + lane];
            #pragma unroll
            for (int c = 0; c < 4; ++c) {
                float f = v[c]; int col = (it * 64 + lane) * 4 + c;
                bool after = (f < pv) || (f == pv && col > pc);  // after prev
                if (f > 0.0f && after) {
                    if (f > bmv || (f == bmv && col < bmc)) { bmv = f; bmc = col; }
                }
            }
        }
        #pragma unroll
        for (int off = 32; off >= 1; off >>= 1) {        // wave argmax
            float ov = __shfl_xor(bmv, off, 64);
            int   oc = __shfl_xor(bmc, off, 64);
            if (ov > bmv || (ov == bmv && oc < bmc)) { bmv = ov; bmc = oc; }
        }
        if (bmv <= 0.0f) break;                          // < K positives
        if (lane == k) { selv = bmv; selc = bmc; }
        pv = bmv; pc = bmc;
    }
    if (selc >= 0) Orow[selc] = selv;
}

extern "C" void kernel_launch(void* const* d_in, const int* in_sizes, int n_in,
                              void* d_out, int out_size, void* d_ws, size_t ws_size,
                              hipStream_t stream) {
    const float* A   = (const float*)d_in[0];
    float*       Out = (float*)d_out;
    (void)in_sizes; (void)n_in; (void)d_ws; (void)ws_size; (void)out_size;
    topk_wave_kernel<<<dim3(N / WPB), dim3(BLOCK), 0, stream>>>(A, Out);
}

// Round 12
// 106.364 us; speedup vs baseline: 5.8481x; 5.8481x over previous
//
#include <hip/hip_runtime.h>

// Row-wise top-K(32) of relu(A), zero elsewhere. N=8192 fp32 per row.
// TWO rows per 512-thread block (waves 0-3 -> row0, waves 4-7 -> row1):
// the 3 per-row block barriers of R8 become 1.5, and the two wave0-only
// selection windows run concurrently (R3/R7/R8: three structures pinned at
// ~92 us with ideal traffic -> per-row fences/selection are the residue;
// R10: wave-per-row can't pipeline loads, 622 us).
// Proven invariants kept:
//  - A read from global EXACTLY ONCE per row (R4)
//  - ONE final nt store burst, NOTHING after it (R5)
//  - O(1)-per-thread emit via per-owner patch slots (R6)
//  - no min-waves forcing in __launch_bounds__ (R1)
// Exact block-uniform fallback: if EITHER row's speculation fails, BOTH rows
// take the full-histogram dense path (no divergent barriers; ~never taken).

constexpr int N     = 8192;
constexpr int K     = 32;
constexpr int HB    = 1024;      // fast: (bits>>20)-1024; fallback: bits>>21
constexpr int CAP   = 512;       // candidates > 2.0 (expected ~186/row)
constexpr int SLOTS = CAP / 64;
constexpr int BB    = 128;       // cutoff-bin members (expected ~26)
constexpr int TPR   = 256;       // threads per row
constexpr int BLOCK = 512;       // 2 rows/block
constexpr int PSLOT = 4;
constexpr float TSPEC = 2.0f;    // bin(2.0): bits>>20 = 1024

typedef float f4 __attribute__((ext_vector_type(4)));

struct Patches { float pval[PSLOT][TPR]; int pcol[PSLOT][TPR]; };
union USpace { unsigned hist[HB]; Patches p; };   // hist dead after cutoff

// Cutoff bin B (bin of the K-th largest) and G = count strictly above B,
// over hist[0..1024). 16 bins/lane, staggered reads (2 lanes/bank: free).
__device__ __forceinline__ bool find_cutoff16(const unsigned* hist, int lane,
                                              int& B, int& G) {
    unsigned s = 0;
    #pragma unroll
    for (int i = 0; i < 16; ++i)
        s += hist[lane * 16 + ((i + lane) & 15)];
    unsigned acc = s;                       // inclusive suffix sum over lanes
    #pragma unroll
    for (int off = 1; off < 64; off <<= 1) {
        unsigned t = __shfl_down(acc, off, 64);
        if (lane + off < 64) acc += t;
    }
    unsigned long long m = __ballot(acc >= (unsigned)K);
    if (m == 0ull) return false;
    int g = 63 - __clzll((long long)m);
    unsigned above = (g < 63) ? (unsigned)__shfl((int)acc, g + 1, 64) : 0u;
    unsigned h  = (lane < 16) ? hist[g * 16 + lane] : 0u;
    unsigned a2 = h;
    #pragma unroll
    for (int off = 1; off < 64; off <<= 1) {
        unsigned t = __shfl_down(a2, off, 64);
        if (lane + off < 64) a2 += t;
    }
    unsigned long long m2 = __ballot(above + a2 >= (unsigned)K);
    int bl = 63 - __clzll((long long)m2);
    B = g * 16 + bl;
    G = (int)(above + (unsigned)__shfl((int)a2, bl, 64)
                    - (unsigned)__shfl((int)h,  bl, 64));
    return true;
}

__global__ __launch_bounds__(BLOCK)
void topk_pair_kernel(const float* __restrict__ A, float* __restrict__ Out) {
    const int tid  = threadIdx.x;
    const int stid = tid & (TPR - 1);     // thread id within the row group
    const int lane = tid & 63;
    const int rw   = (tid >> 6) & 3;      // wave index within the row group
    const int sub  = tid >> 8;            // which row of the pair
    const int row  = blockIdx.x * 2 + sub;

    __shared__ USpace   u[2];             // 16 KB
    __shared__ float    cv[2][CAP];       // 4 KB
    __shared__ int      cc[2][CAP];       // 4 KB
    __shared__ float    bbv[2][BB];       // 1 KB
    __shared__ int      bbc[2][BB];       // 1 KB
    __shared__ unsigned pcnt[2][TPR];     // 2 KB
    __shared__ unsigned ccnt[2];
    __shared__ int      fb;               // combined fallback flag

    #pragma unroll
    for (int i = 0; i < HB / TPR; ++i) u[sub].hist[stid + i * TPR] = 0u;
    pcnt[sub][stid] = 0u;
    if (stid == 0) ccnt[sub] = 0u;
    if (tid == 0) fb = 0;
    __syncthreads();                                   // barrier 1 (per pair)

    // ---- touch 1: the ONLY global read of A on the fast path ----
    const f4* __restrict__ Arow = reinterpret_cast<const f4*>(A + (size_t)row * N);
    #pragma unroll
    for (int i = 0; i < 8; ++i) {
        f4 v = Arow[i * TPR + stid];
        #pragma unroll
        for (int c = 0; c < 4; ++c) {
            float f = v[c];
            if (f > TSPEC) {
                atomicAdd(&u[sub].hist[(__float_as_uint(f) >> 20) - 1024], 1u);
                unsigned ix = atomicAdd(&ccnt[sub], 1u);
                if (ix < CAP) {
                    cv[sub][ix] = f;
                    cc[sub][ix] = (i * TPR + stid) * 4 + c;
                }
            }
        }
    }
    __syncthreads();                                   // barrier 2 (per pair)

    f4* __restrict__ Orow4 = reinterpret_cast<f4*>(Out + (size_t)row * N);

    // ---- selection: one wave per row, both rows concurrently ----
    if (rw == 0) {
        int B, G;
        bool ok = find_cutoff16(u[sub].hist, lane, B, G);
        const unsigned Call = ccnt[sub];
        if (!ok || Call > (unsigned)CAP) { fb = 1; }
        else {
            const int R = K - G;
            const int C = (int)Call;
            int total = 0;
            #pragma unroll
            for (int s = 0; s < SLOTS; ++s) {
                const int j = lane + s * 64;
                bool flag = false; float fv = 0.0f; int fc = 0;
                if (j < C) {
                    fv = cv[sub][j];
                    if ((int)((__float_as_uint(fv) >> 20) - 1024) == B) {
                        flag = true; fc = cc[sub][j];
                    }
                }
                unsigned long long m = __ballot(flag);
                if (flag) {
                    int pos = total + __popcll(m & ((1ull << lane) - 1ull));
                    if (pos < BB) { bbv[sub][pos] = fv; bbc[sub][pos] = fc; }
                }
                total += (int)__popcll(m);
            }
            if (total > BB) { fb = 1; }
            else {
                const int T = total;                   // expected ~26; >= R
                float mv0 = -1.0f, mv1 = -1.0f;
                int   mc0 = 0x7fffffff, mc1 = 0x7fffffff;
                if (lane      < T) { mv0 = bbv[sub][lane];      mc0 = bbc[sub][lane]; }
                if (lane + 64 < T) { mv1 = bbv[sub][lane + 64]; mc1 = bbc[sub][lane + 64]; }
                int r0 = 0, r1 = 0;
                for (int j = 0; j < T; ++j) {          // LDS broadcast reads
                    const float vj = bbv[sub][j];
                    const int   cj = bbc[sub][j];
                    if (vj > mv0 || (vj == mv0 && cj < mc0)) r0++;
                    if (vj > mv1 || (vj == mv1 && cj < mc1)) r1++;
                }
                float bv = 0.0f; int bc = -1; bool found = false;
                if (lane      < T && r0 == R - 1) { bv = mv0; bc = mc0; found = true; }
                if (lane + 64 < T && r1 == R - 1) { bv = mv1; bc = mc1; found = true; }
                float vR = __int_as_float(0x7f800000);
                int   cR = -1;
                unsigned long long bm = __ballot(found);
                if (bm != 0ull) {
                    int src = (int)__ffsll((long long)bm) - 1;
                    vR = __shfl(bv, src, 64);
                    cR = __shfl(bc, src, 64);
                }
                // scatter exactly-K selected pairs to owner threads
                // (overwrites u[sub].hist — dead; same-wave LDS in-order)
                #pragma unroll
                for (int s = 0; s < SLOTS; ++s) {
                    const int j = lane + s * 64;
                    if (j < C) {
                        float fv = cv[sub][j]; int fc = cc[sub][j];
                        if (fv > vR || (fv == vR && fc <= cR)) {
                            int owner = (fc >> 2) & (TPR - 1);
                            unsigned p = atomicAdd(&pcnt[sub][owner], 1u);
                            if (p < (unsigned)PSLOT) {
                                u[sub].p.pval[p][owner] = fv;
                                u[sub].p.pcol[p][owner] = fc;
                            } else fb = 1;             // rare
                        }
                    }
                }
            }
        }
    }
    __syncthreads();                                   // barrier 3 (per pair)

    if (!fb) {
        // ---- emit: zero + own patches; ONE nt burst, kernel ends ----
        const unsigned cnt = pcnt[sub][stid];
        const float v0 = u[sub].p.pval[0][stid], v1 = u[sub].p.pval[1][stid],
                    v2 = u[sub].p.pval[2][stid], v3 = u[sub].p.pval[3][stid];
        const int   c0 = u[sub].p.pcol[0][stid], c1 = u[sub].p.pcol[1][stid],
                    c2 = u[sub].p.pcol[2][stid], c3 = u[sub].p.pcol[3][stid];
        unsigned m8 = 0;
        if (cnt > 0) m8 |= 1u << (c0 >> 10);
        if (cnt > 1) m8 |= 1u << (c1 >> 10);
        if (cnt > 2) m8 |= 1u << (c2 >> 10);
        if (cnt > 3) m8 |= 1u << (c3 >> 10);
        #pragma unroll
        for (int i = 0; i < 8; ++i) {
            f4 w = {0.0f, 0.0f, 0.0f, 0.0f};
            if (m8 & (1u << i)) {
                #define APPLY(CC, VV, KI)                                          \
                    if (cnt > (KI) && ((CC) >> 10) == i) {                         \
                        const int cm = (CC) & 3;                                   \
                        w[0] = (cm == 0) ? (VV) : w[0];                            \
                        w[1] = (cm == 1) ? (VV) : w[1];                            \
                        w[2] = (cm == 2) ? (VV) : w[2];                            \
                        w[3] = (cm == 3) ? (VV) : w[3];                            \
                    }
                APPLY(c0, v0, 0) APPLY(c1, v1, 1) APPLY(c2, v2, 2) APPLY(c3, v3, 3)
                #undef APPLY
            }
            __builtin_nontemporal_store(w, Orow4 + i * TPR + stid);
        }
        return;
    }

    // ---- exact fallback: BOTH rows dense (block-uniform; ~never) ----
    #pragma unroll
    for (int i = 0; i < HB / TPR; ++i) u[sub].hist[stid + i * TPR] = 0u;
    if (stid == 0) ccnt[sub] = 0u;
    __syncthreads();
    #pragma unroll
    for (int i = 0; i < 8; ++i) {
        f4 v = Arow[i * TPR + stid];
        #pragma unroll
        for (int c = 0; c < 4; ++c) {
            float f = v[c];
            if (f > 0.0f) atomicAdd(&u[sub].hist[__float_as_uint(f) >> 21], 1u);
        }
    }
    __syncthreads();
    int B, G;
    if (!find_cutoff16(u[sub].hist, lane, B, G)) { B = -1; G = 0; }
    if (B >= 0) {
        #pragma unroll
        for (int i = 0; i < 8; ++i) {
            f4 v = Arow[i * TPR + stid];
            #pragma unroll
            for (int c = 0; c < 4; ++c) {
                float f = v[c];
                if (f > 0.0f && (int)(__float_as_uint(f) >> 21) == B) {
                    unsigned ix = atomicAdd(&ccnt[sub], 1u);
                    if (ix < CAP) {
                        cv[sub][ix] = f;
                        cc[sub][ix] = (i * TPR + stid) * 4 + c;
                    }
                }
            }
        }
    }
    __syncthreads();

    float vR = 0.0f;                        // B == -1: keep all positives
    int   cR = -1;
    if (B >= 0) {
        const int R = K - G;
        const int C = (int)min(ccnt[sub], (unsigned)CAP);
        float mv[SLOTS]; int mc[SLOTS]; int rk[SLOTS];
        #pragma unroll
        for (int s = 0; s < SLOTS; ++s) {
            const int j = lane + s * 64;
            if (j < C) { mv[s] = cv[sub][j]; mc[s] = cc[sub][j]; }
            else       { mv[s] = -1.0f;      mc[s] = 0x7fffffff; }
            rk[s] = 0;
        }
        for (int j = 0; j < C; ++j) {
            const float vj = cv[sub][j];
            const int   cj = cc[sub][j];
            #pragma unroll
            for (int s = 0; s < SLOTS; ++s)
                if (vj > mv[s] || (vj == mv[s] && cj < mc[s])) rk[s]++;
        }
        float bv = 0.0f; int bc = -1; bool found = false;
        #pragma unroll
        for (int s = 0; s < SLOTS; ++s)
            if (lane + s * 64 < C && rk[s] == R - 1) { bv = mv[s]; bc = mc[s]; found = true; }
        vR = __int_as_float(0x7f800000);
        unsigned long long bm = __ballot(found);
        if (bm != 0ull) {
            int src = (int)__ffsll((long long)bm) - 1;
            vR = __shfl(bv, src, 64);
            cR = __shfl(bc, src, 64);
        }
    }
    // dense emit (fallback only): re-read row (cache-hot) and write all
    #pragma unroll
    for (int i = 0; i < 8; ++i) {
        f4 v = Arow[i * TPR + stid];
        f4 w;
        #pragma unroll
        for (int c = 0; c < 4; ++c) {
            float f   = v[c];
            int   col = (i * TPR + stid) * 4 + c;
            w[c] = ((f > vR) || (f == vR && col <= cR)) ? f : 0.0f;
        }
        __builtin_nontemporal_store(w, Orow4 + i * TPR + stid);
    }
}

extern "C" void kernel_launch(void* const* d_in, const int* in_sizes, int n_in,
                              void* d_out, int out_size, void* d_ws, size_t ws_size,
                              hipStream_t stream) {
    const float* A   = (const float*)d_in[0];
    float*       Out = (float*)d_out;
    (void)in_sizes; (void)n_in; (void)d_ws; (void)ws_size; (void)out_size;
    topk_pair_kernel<<<dim3(N / 2), dim3(BLOCK), 0, stream>>>(A, Out);
}

// Round 13
// 91.942 us; speedup vs baseline: 6.7655x; 1.1569x over previous
//
#include <hip/hip_runtime.h>

// Row-wise top-K(32) of relu(A), zero elsewhere. N=8192 fp32 per row.
// One 256-thread block per row.  [PROVEN BEST: 91.8 us, R8]
//  - A read from global EXACTLY ONCE   (R4: 2nd stream kills L3 residency)
//  - ONE final nt store burst, NOTHING after it (R5: post-store vm-drain
//    barrier costs ~12 us)
//  - O(1)-per-thread emit via per-owner patch slots (R6: per-chunk LDS
//    search was ~3000 cyc/wave)
//  - small blocks, 3 narrow barriers (R11: 512-thread pairing -> 106 us;
//    R9: kernel split -> 115 us; R10: wave-per-row -> 622 us)
// Flow: touch1 = hist(values>2.0, (bits>>20)-1024) + collect (val,col)>2.0
// into LDS (~186). Wave 0: cutoff bin B, exact (val desc, col asc) rank-R
// boundary, scatter the exactly-K selected pairs to per-owner patch slots
// (owner=(col>>2)&255, <=4 slots, transposed). One LDS barrier. Emit 8 f4
// nt stores per thread (zero except own patches). Exact block-uniform
// fallback (coarser bits>>21 full-range histogram + dense reload-emit).

constexpr int N     = 8192;
constexpr int K     = 32;
constexpr int HB    = 1024;      // histogram bins (both paths)
constexpr int CAP   = 512;       // candidate list capacity (expected ~186)
constexpr int SLOTS = CAP / 64;
constexpr int BB    = 128;       // compacted cutoff-bin entries
constexpr int BLOCK = 256;
constexpr int PSLOT = 4;         // patch slots per owner thread
constexpr float TSPEC = 2.0f;    // bin(2.0): bits>>20 = 1024

typedef float f4 __attribute__((ext_vector_type(4)));

// Cutoff bin B (bin of the K-th largest) and G = count strictly above B,
// over hist[0..1024). PER=16 bins/lane, staggered reads (2 lanes/bank).
__device__ __forceinline__ bool find_cutoff16(const unsigned* hist, int lane,
                                              int& B, int& G) {
    unsigned s = 0;
    #pragma unroll
    for (int i = 0; i < 16; ++i)
        s += hist[lane * 16 + ((i + lane) & 15)];
    unsigned acc = s;                       // inclusive suffix sum over lanes
    #pragma unroll
    for (int off = 1; off < 64; off <<= 1) {
        unsigned t = __shfl_down(acc, off, 64);
        if (lane + off < 64) acc += t;
    }
    unsigned long long m = __ballot(acc >= (unsigned)K);
    if (m == 0ull) return false;
    int g = 63 - __clzll((long long)m);     // highest group with suffix >= K
    unsigned above = (g < 63) ? (unsigned)__shfl((int)acc, g + 1, 64) : 0u;
    unsigned h  = (lane < 16) ? hist[g * 16 + lane] : 0u;
    unsigned a2 = h;                        // within-group suffix
    #pragma unroll
    for (int off = 1; off < 64; off <<= 1) {
        unsigned t = __shfl_down(a2, off, 64);
        if (lane + off < 64) a2 += t;
    }
    unsigned long long m2 = __ballot(above + a2 >= (unsigned)K);
    int bl = 63 - __clzll((long long)m2);
    B = g * 16 + bl;
    G = (int)(above + (unsigned)__shfl((int)a2, bl, 64)
                    - (unsigned)__shfl((int)h,  bl, 64));
    return true;
}

struct Patches {
    float pval[PSLOT][BLOCK];    // transposed: stride-1 reads at emit
    int   pcol[PSLOT][BLOCK];
};
union USpace {                   // hist dead after find_cutoff -> reuse
    unsigned hist[HB];           // 4 KB
    Patches  p;                  // 8 KB
};

__global__ __launch_bounds__(BLOCK)
void topk_relu_kernel(const float* __restrict__ A, float* __restrict__ Out) {
    const int row  = blockIdx.x;
    const int tid  = threadIdx.x;
    const int lane = tid & 63;
    const int wave = tid >> 6;

    __shared__ USpace   u;
    __shared__ float    cv[CAP];
    __shared__ int      cc[CAP];
    __shared__ float    bbv[BB];
    __shared__ int      bbc[BB];
    __shared__ unsigned pcnt[BLOCK];
    __shared__ unsigned ccnt;
    __shared__ int      fb;

    #pragma unroll
    for (int i = 0; i < HB / BLOCK; ++i) u.hist[tid + i * BLOCK] = 0u;
    pcnt[tid] = 0u;
    if (tid == 0) { ccnt = 0u; fb = 0; }
    __syncthreads();

    // ---- touch 1: the ONLY global read of A on the fast path ----
    const f4* __restrict__ Arow = reinterpret_cast<const f4*>(A + (size_t)row * N);
    #pragma unroll
    for (int i = 0; i < 8; ++i) {
        f4 v = Arow[i * BLOCK + tid];
        #pragma unroll
        for (int c = 0; c < 4; ++c) {
            float f = v[c];
            if (f > TSPEC) {
                atomicAdd(&u.hist[(__float_as_uint(f) >> 20) - 1024], 1u);
                unsigned ix = atomicAdd(&ccnt, 1u);
                if (ix < CAP) { cv[ix] = f; cc[ix] = (i * BLOCK + tid) * 4 + c; }
            }
        }
    }
    __syncthreads();

    f4* __restrict__ Orow4 = reinterpret_cast<f4*>(Out + (size_t)row * N);

    // ---- selection: WAVE 0 ONLY (waves 1-3 fall through to the barrier) ----
    if (wave == 0) {
        int B, G;
        bool ok = find_cutoff16(u.hist, lane, B, G);
        const unsigned Call = ccnt;
        if (!ok || Call > (unsigned)CAP) {
            fb = 1;
        } else {
            const int R = K - G;            // boundary rank within bin B (>=1)
            const int C = (int)Call;
            // compact bin-B entries into bbv/bbc
            int total = 0;
            #pragma unroll
            for (int s = 0; s < SLOTS; ++s) {
                const int j = lane + s * 64;
                bool flag = false; float fv = 0.0f; int fc = 0;
                if (j < C) {
                    fv = cv[j];
                    if ((int)((__float_as_uint(fv) >> 20) - 1024) == B) {
                        flag = true; fc = cc[j];
                    }
                }
                unsigned long long m = __ballot(flag);
                if (flag) {
                    int pos = total + __popcll(m & ((1ull << lane) - 1ull));
                    if (pos < BB) { bbv[pos] = fv; bbc[pos] = fc; }
                }
                total += (int)__popcll(m);
            }
            if (total > BB) {
                fb = 1;                     // adversarial tie overflow
            } else {
                const int T = total;        // expected ~26; >= R
                float mv0 = -1.0f, mv1 = -1.0f; int mc0 = 0x7fffffff, mc1 = 0x7fffffff;
                if (lane      < T) { mv0 = bbv[lane];      mc0 = bbc[lane]; }
                if (lane + 64 < T) { mv1 = bbv[lane + 64]; mc1 = bbc[lane + 64]; }
                int r0 = 0, r1 = 0;
                for (int j = 0; j < T; ++j) {    // LDS broadcast reads
                    const float vj = bbv[j];
                    const int   cj = bbc[j];
                    if (vj > mv0 || (vj == mv0 && cj < mc0)) r0++;
                    if (vj > mv1 || (vj == mv1 && cj < mc1)) r1++;
                }
                float bv = 0.0f; int bc = -1; bool found = false;
                if (lane      < T && r0 == R - 1) { bv = mv0; bc = mc0; found = true; }
                if (lane + 64 < T && r1 == R - 1) { bv = mv1; bc = mc1; found = true; }
                float vR = __int_as_float(0x7f800000);
                int   cR = -1;
                unsigned long long bm = __ballot(found);
                if (bm != 0ull) {
                    int src = (int)__ffsll((long long)bm) - 1;
                    vR = __shfl(bv, src, 64);
                    cR = __shfl(bc, src, 64);
                }
                // scatter the exactly-K selected pairs to their owner threads.
                // Overwrites u.hist (dead): same-wave LDS ops are in-order.
                #pragma unroll
                for (int s = 0; s < SLOTS; ++s) {
                    const int j = lane + s * 64;
                    if (j < C) {
                        float fv = cv[j]; int fc = cc[j];
                        if (fv > vR || (fv == vR && fc <= cR)) {
                            int owner = (fc >> 2) & (BLOCK - 1);
                            unsigned p = atomicAdd(&pcnt[owner], 1u);
                            if (p < (unsigned)PSLOT) {
                                u.p.pval[p][owner] = fv;
                                u.p.pcol[p][owner] = fc;
                            } else {
                                fb = 1;     // >PSLOT per owner (rare)
                            }
                        }
                    }
                }
            }
        }
    }
    __syncthreads();   // LDS-only barrier: no global stores outstanding

    if (!fb) {
        // ---- emit: zero + own patches; ONE nt burst, kernel ends ----
        const unsigned cnt = pcnt[tid];
        const float v0 = u.p.pval[0][tid], v1 = u.p.pval[1][tid],
                    v2 = u.p.pval[2][tid], v3 = u.p.pval[3][tid];
        const int   c0 = u.p.pcol[0][tid], c1 = u.p.pcol[1][tid],
                    c2 = u.p.pcol[2][tid], c3 = u.p.pcol[3][tid];
        unsigned m8 = 0;
        if (cnt > 0) m8 |= 1u << (c0 >> 10);
        if (cnt > 1) m8 |= 1u << (c1 >> 10);
        if (cnt > 2) m8 |= 1u << (c2 >> 10);
        if (cnt > 3) m8 |= 1u << (c3 >> 10);
        #pragma unroll
        for (int i = 0; i < 8; ++i) {
            f4 w = {0.0f, 0.0f, 0.0f, 0.0f};
            if (m8 & (1u << i)) {
                #define APPLY(CC, VV, KI)                                          \
                    if (cnt > (KI) && ((CC) >> 10) == i) {                         \
                        const int cm = (CC) & 3;                                   \
                        w[0] = (cm == 0) ? (VV) : w[0];                            \
                        w[1] = (cm == 1) ? (VV) : w[1];                            \
                        w[2] = (cm == 2) ? (VV) : w[2];                            \
                        w[3] = (cm == 3) ? (VV) : w[3];                            \
                    }
                APPLY(c0, v0, 0) APPLY(c1, v1, 1) APPLY(c2, v2, 2) APPLY(c3, v3, 3)
                #undef APPLY
            }
            __builtin_nontemporal_store(w, Orow4 + i * BLOCK + tid);
        }
        return;
    }

    // ---- exact fallback (block-uniform; ~never for N(0,1) rows) ----
    // coarser full-range binning: bits>>21 in [0, 1024), still monotonic.
    #pragma unroll
    for (int i = 0; i < HB / BLOCK; ++i) u.hist[tid + i * BLOCK] = 0u;
    if (tid == 0) ccnt = 0u;
    __syncthreads();
    #pragma unroll
    for (int i = 0; i < 8; ++i) {
        f4 v = Arow[i * BLOCK + tid];
        #pragma unroll
        for (int c = 0; c < 4; ++c) {
            float f = v[c];
            if (f > 0.0f) atomicAdd(&u.hist[__float_as_uint(f) >> 21], 1u);
        }
    }
    __syncthreads();
    int B, G;
    if (!find_cutoff16(u.hist, lane, B, G)) { B = -1; G = 0; }
    if (B >= 0) {
        #pragma unroll
        for (int i = 0; i < 8; ++i) {
            f4 v = Arow[i * BLOCK + tid];
            #pragma unroll
            for (int c = 0; c < 4; ++c) {
                float f = v[c];
                if (f > 0.0f && (int)(__float_as_uint(f) >> 21) == B) {
                    unsigned ix = atomicAdd(&ccnt, 1u);
                    if (ix < CAP) { cv[ix] = f; cc[ix] = (i * BLOCK + tid) * 4 + c; }
                }
            }
        }
    }
    __syncthreads();

    float vR = 0.0f;                        // B == -1: keep all positives
    int   cR = -1;
    if (B >= 0) {
        const int R = K - G;
        const int C = (int)min(ccnt, (unsigned)CAP);
        float mv[SLOTS]; int mc[SLOTS]; int rk[SLOTS];
        #pragma unroll
        for (int s = 0; s < SLOTS; ++s) {
            const int j = lane + s * 64;
            if (j < C) { mv[s] = cv[j]; mc[s] = cc[j]; }
            else       { mv[s] = -1.0f; mc[s] = 0x7fffffff; }
            rk[s] = 0;
        }
        for (int j = 0; j < C; ++j) {
            const float vj = cv[j];
            const int   cj = cc[j];
            #pragma unroll
            for (int s = 0; s < SLOTS; ++s)
                if (vj > mv[s] || (vj == mv[s] && cj < mc[s])) rk[s]++;
        }
        float bv = 0.0f; int bc = -1; bool found = false;
        #pragma unroll
        for (int s = 0; s < SLOTS; ++s)
            if (lane + s * 64 < C && rk[s] == R - 1) { bv = mv[s]; bc = mc[s]; found = true; }
        vR = __int_as_float(0x7f800000);
        unsigned long long bm = __ballot(found);
        if (bm != 0ull) {
            int src = (int)__ffsll((long long)bm) - 1;
            vR = __shfl(bv, src, 64);
            cR = __shfl(bc, src, 64);
        }
    }

    // dense emit (fallback only): re-read row (cache-hot) and write all
    #pragma unroll
    for (int i = 0; i < 8; ++i) {
        f4 v = Arow[i * BLOCK + tid];
        f4 w;
        #pragma unroll
        for (int c = 0; c < 4; ++c) {
            float f   = v[c];
            int   col = (i * BLOCK + tid) * 4 + c;
            w[c] = ((f > vR) || (f == vR && col <= cR)) ? f : 0.0f;
        }
        __builtin_nontemporal_store(w, Orow4 + i * BLOCK + tid);
    }
}

extern "C" void kernel_launch(void* const* d_in, const int* in_sizes, int n_in,
                              void* d_out, int out_size, void* d_ws, size_t ws_size,
                              hipStream_t stream) {
    const float* A   = (const float*)d_in[0];
    float*       Out = (float*)d_out;
    (void)in_sizes; (void)n_in; (void)d_ws; (void)ws_size; (void)out_size;
    topk_relu_kernel<<<dim3(N), dim3(BLOCK), 0, stream>>>(A, Out);
}